// Round 10
// baseline (322.849 us; speedup 1.0000x reference)
//
#include <hip/hip_runtime.h>
#include <hip/hip_bf16.h>

typedef __hip_bfloat16 bf16;
typedef unsigned short u16;
typedef unsigned int u32;

__device__ __forceinline__ float bf2f(bf16 v) { return __bfloat162float(v); }
__device__ __forceinline__ float us2f(u16 u) {
    union { u32 i; float f; } c; c.i = ((u32)u) << 16; return c.f;
}
// unpack 8 bf16 (packed in uint4) -> 8 floats
__device__ __forceinline__ void up8(const uint4 v, float* f) {
    f[0] = us2f((u16)(v.x & 0xffff)); f[1] = us2f((u16)(v.x >> 16));
    f[2] = us2f((u16)(v.y & 0xffff)); f[3] = us2f((u16)(v.y >> 16));
    f[4] = us2f((u16)(v.z & 0xffff)); f[5] = us2f((u16)(v.z >> 16));
    f[6] = us2f((u16)(v.w & 0xffff)); f[7] = us2f((u16)(v.w >> 16));
}

// ---------------------------------------------------------------------------
// K1: km/qm/xm = conv1x1(x,{wk,wq,wx}) (+bias, km*=vessel), bf16 out,
// channel-last [pixel][32]. Restructured vs r9: 512 blocks x 32 px
// (2 blocks/CU), 256 thr = 8 og x 32 px (12 outputs each, low VGPR),
// xs pad 80 (stride mod 32 = 16 -> 2-way LDS, free). wch reads are
// wave-uniform broadcasts. LDS 34.8 KB.
// ---------------------------------------------------------------------------
__global__ __launch_bounds__(256, 4) void k_proj(
    const float* __restrict__ x, const float* __restrict__ vessel,
    const float* __restrict__ wk, const float* __restrict__ bk,
    const float* __restrict__ wq, const float* __restrict__ bq,
    const float* __restrict__ wx, const float* __restrict__ bx,
    bf16* __restrict__ km, bf16* __restrict__ qm, bf16* __restrict__ xm)
{
    __shared__ float xs[32 * 80];    // [px][cc] pad 80 (10240 B)
    __shared__ float wch[96 * 64];   // [o][cc]  (24576 B)
    const int tid = threadIdx.x;
    const int og = tid >> 5, px = tid & 31;      // 8 og x 32 px
    const int b = blockIdx.x >> 7;
    const int p0 = (blockIdx.x & 127) * 32;

    float acc[12];
#pragma unroll
    for (int j = 0; j < 12; ++j) {
        const int o = og * 12 + j;
        const float* bs = (o < 32) ? bk : ((o < 64) ? bq : bx);
        acc[j] = bs[o & 31];
    }
    for (int c0 = 0; c0 < 256; c0 += 64) {
        __syncthreads();
#pragma unroll
        for (int i = 0; i < 24; ++i) {           // 96x64 weights
            const int idx = tid + i * 256;
            const int o = idx >> 6, cc = idx & 63;
            const float* wp = (o < 32) ? wk : ((o < 64) ? wq : wx);
            wch[o * 64 + cc] = wp[(o & 31) * 256 + c0 + cc];
        }
#pragma unroll
        for (int i = 0; i < 8; ++i) {            // 64cc x 32px
            const int idx = tid + i * 256;
            const int cc = idx >> 5, pl = idx & 31;
            xs[pl * 80 + cc] = x[(b * 256 + c0 + cc) * 4096 + p0 + pl];
        }
        __syncthreads();
#pragma unroll
        for (int c4 = 0; c4 < 16; ++c4) {
            const float4 xv = *(const float4*)&xs[px * 80 + c4 * 4];
#pragma unroll
            for (int j = 0; j < 12; ++j) {
                const float4 wv = *(const float4*)&wch[(og * 12 + j) * 64 + c4 * 4];
                acc[j] += wv.x * xv.x + wv.y * xv.y + wv.z * xv.z + wv.w * xv.w;
            }
        }
    }
    const float v = vessel[b * 4096 + p0 + px];
    const int gp = (b * 4096 + p0 + px) * 32;
#pragma unroll
    for (int j = 0; j < 12; ++j) {
        const int o = og * 12 + j;
        const int ch = o & 31;
        if (o < 32)      km[gp + ch] = __float2bfloat16(acc[j] * v);
        else if (o < 64) qm[gp + ch] = __float2bfloat16(acc[j]);
        else             xm[gp + ch] = __float2bfloat16(acc[j]);
    }
}

// ---------------------------------------------------------------------------
// K2: 4-scale local attention, nested-window fusion. vs r9: LDS rows
// 16B-aligned (stride 40 u16) read as uint4 (8 bf16/inst, was 8 scalar
// ds_read_u16); pass-1 exponentials cached in sc[] so pass 2 skips the
// dot+shuffle recompute. OOB halo = 0 => s = 0 matches reference
// zero-padding in the softmax denominator. LDS 61 KB.
// ---------------------------------------------------------------------------
__global__ __launch_bounds__(256) void k_attn(
    const bf16* __restrict__ km, const bf16* __restrict__ qm,
    const bf16* __restrict__ xm, bf16* __restrict__ pre)
{
    __shared__ u16 kT[256 * 40];     // 20480 B
    __shared__ u16 xT[256 * 40];     // 20480 B
    __shared__ float sc[64 * 84];    // 21504 B
    const int tid = threadIdx.x;
    const int b = blockIdx.x >> 6;
    const int tile = blockIdx.x & 63;
    const int h0 = (tile >> 3) * 8, w0 = (tile & 7) * 8;
    const u16* uk = (const u16*)km;
    const u16* ux = (const u16*)xm;

    const uint4 z4 = {0u, 0u, 0u, 0u};
#pragma unroll
    for (int i = 0; i < 4; ++i) {
        const int idx4 = tid + i * 256;          // 0..1023 uint4 groups
        const int pos = idx4 >> 2, c8 = idx4 & 3;
        const int gh = h0 - 4 + (pos >> 4), gw = w0 - 4 + (pos & 15);
        uint4 kv = z4, xv = z4;
        if (gh >= 0 && gh < 64 && gw >= 0 && gw < 64) {
            const int g = ((b << 12) + (gh << 6) + gw) * 32 + c8 * 8;
            kv = *(const uint4*)&uk[g];
            xv = *(const uint4*)&ux[g];
        }
        *(uint4*)&kT[pos * 40 + c8 * 8] = kv;
        *(uint4*)&xT[pos * 40 + c8 * 8] = xv;
    }
    const int px = tid >> 2, cg = tid & 3;
    const int py = px >> 3, pxx = px & 7;
    const int gp = ((b << 12) + ((h0 + py) << 6) + (w0 + pxx)) * 32;
    float q[8];
    up8(*(const uint4*)&((const u16*)qm)[gp + cg * 8], q);
    __syncthreads();

    // pass 1: dots over the 9x9 superset; e cached in sc; ring sums
    float Z3 = 0.f, Z5 = 0.f, Z7 = 0.f, Z9 = 0.f;
    for (int j = 0; j < 81; ++j) {
        const int jd = j / 9;
        const int dy = jd - 4, dx = j - jd * 9 - 4;
        const int pos = (py + 4 + dy) * 16 + (pxx + 4 + dx);
        float kf[8];
        up8(*(const uint4*)&kT[pos * 40 + cg * 8], kf);
        float s = kf[0]*q[0] + kf[1]*q[1] + kf[2]*q[2] + kf[3]*q[3]
                + kf[4]*q[4] + kf[5]*q[5] + kf[6]*q[6] + kf[7]*q[7];
        s += __shfl_xor(s, 1);
        s += __shfl_xor(s, 2);
        const float e = __expf(s);
        if (cg == 0) sc[px * 84 + j] = e;
        const int ady = dy < 0 ? -dy : dy, adx = dx < 0 ? -dx : dx;
        const int r = ady > adx ? ady : adx;
        if (r <= 1) Z3 += e;
        if (r <= 2) Z5 += e;
        if (r <= 3) Z7 += e;
        Z9 += e;
    }
    const float iZ3 = 1.f / Z3, iZ5 = 1.f / Z5, iZ7 = 1.f / Z7, iZ9 = 1.f / Z9;
    __syncthreads();

    // pass 2: weighted value accumulation from cached e
    float acc[8];
#pragma unroll
    for (int i = 0; i < 8; ++i) acc[i] = 0.f;
    for (int j = 0; j < 81; ++j) {
        const int jd = j / 9;
        const int dy = jd - 4, dx = j - jd * 9 - 4;
        const int pos = (py + 4 + dy) * 16 + (pxx + 4 + dx);
        const float e = sc[px * 84 + j];
        const int ady = dy < 0 ? -dy : dy, adx = dx < 0 ? -dx : dx;
        const int r = ady > adx ? ady : adx;
        float coef = iZ9;
        if (r <= 1) coef += iZ3;
        if (r <= 2) coef += iZ5;
        if (r <= 3) coef += iZ7;
        const float w = e * coef;
        float xf[8];
        up8(*(const uint4*)&xT[pos * 40 + cg * 8], xf);
#pragma unroll
        for (int i = 0; i < 8; ++i) acc[i] += w * xf[i];
    }
#pragma unroll
    for (int i = 0; i < 8; ++i) pre[gp + cg * 8 + i] = __float2bfloat16(acc[i]);
}

// ---------------------------------------------------------------------------
// K2b: partial S2 = pre^T pre (32x32) + S1 = sum(pre), 256 px/blk
// ---------------------------------------------------------------------------
__global__ __launch_bounds__(256) void k_cov(
    const bf16* __restrict__ pre, float* __restrict__ partials)
{
    __shared__ float t[256 * 32];
    const int tid = threadIdx.x;
    const int p0 = blockIdx.x * 256;
    for (int i = 0; i < 32; ++i) {
        const int idx = tid + i * 256;
        t[idx] = bf2f(pre[p0 * 32 + idx]);
    }
    __syncthreads();
    const int i0 = tid >> 3, j0 = (tid & 7) * 4;
    float4 a = {0.f, 0.f, 0.f, 0.f};
    for (int p = 0; p < 256; ++p) {
        const float vi = t[p * 32 + i0];
        const float4 vj = *(const float4*)&t[p * 32 + j0];
        a.x += vi * vj.x; a.y += vi * vj.y; a.z += vi * vj.z; a.w += vi * vj.w;
    }
    *(float4*)&partials[blockIdx.x * 1056 + i0 * 32 + j0] = a;
    if (tid < 32) {
        float s = 0.f;
        for (int p = 0; p < 256; ++p) s += t[p * 32 + tid];
        partials[blockIdx.x * 1056 + 1024 + tid] = s;
    }
}

// ---------------------------------------------------------------------------
// K2c: BN constants. meanY[o]=wf_o.mu+bf[o]; var=wf_o S2 wf_o^T/N-(wf_o.mu)^2
// A = gamma*rsqrt(var+eps); S = beta - A*meanY (k_out adds bf into y).
// ---------------------------------------------------------------------------
__global__ __launch_bounds__(256) void k_stats(
    const float* __restrict__ partials, const float* __restrict__ wf,
    const float* __restrict__ bfb, const float* __restrict__ gamma,
    const float* __restrict__ beta,
    float* __restrict__ Aout, float* __restrict__ Sout)
{
    __shared__ float cov[1024];
    __shared__ float mu[32];
    const int tid = threadIdx.x;
    float4 a = {0.f, 0.f, 0.f, 0.f};
    for (int blk = 0; blk < 64; ++blk) {
        const float4 p = *(const float4*)&partials[blk * 1056 + tid * 4];
        a.x += p.x; a.y += p.y; a.z += p.z; a.w += p.w;
    }
    *(float4*)&cov[tid * 4] = a;
    if (tid < 32) {
        float s = 0.f;
        for (int blk = 0; blk < 64; ++blk) s += partials[blk * 1056 + 1024 + tid];
        mu[tid] = s * (1.f / 16384.f);
    }
    __syncthreads();
    float wo[32];
#pragma unroll
    for (int c = 0; c < 32; ++c) wo[c] = wf[tid * 32 + c];
    float mv = 0.f;
#pragma unroll
    for (int c = 0; c < 32; ++c) mv += wo[c] * mu[c];
    float qacc = 0.f;
    for (int i2 = 0; i2 < 32; ++i2) {
        float t = 0.f;
#pragma unroll
        for (int j2 = 0; j2 < 32; ++j2) t += wo[j2] * cov[i2 * 32 + j2];
        qacc += wo[i2] * t;
    }
    const float var = qacc * (1.f / 16384.f) - mv * mv;
    const float A = gamma[tid] * rsqrtf(var + 1e-5f);
    Aout[tid] = A;
    Sout[tid] = beta[tid] - A * (mv + bfb[tid]);
}

// ---------------------------------------------------------------------------
// K3: out = x + A*(wf.pre + bf) + S, f32 out. Register-blocked (r9 PASS).
// ---------------------------------------------------------------------------
__global__ __launch_bounds__(256) void k_out(
    const bf16* __restrict__ pre, const float* __restrict__ wf,
    const float* __restrict__ bfb, const float* __restrict__ x,
    const float* __restrict__ A, const float* __restrict__ S,
    float* __restrict__ out)
{
    __shared__ float wfL[256 * 32];  // 32768 B
    __shared__ float pL[64 * 36];    //  9216 B
    const int tid = threadIdx.x;
    const int gp0 = blockIdx.x * 64;
    const int b = gp0 >> 12, p0 = gp0 & 4095;
#pragma unroll
    for (int i = 0; i < 8; ++i) {
        const int idx4 = tid + i * 256;
        *(float4*)&wfL[idx4 * 4] = *(const float4*)&wf[idx4 * 4];
    }
    for (int i = 0; i < 8; ++i) {
        const int idx = tid + i * 256;
        const int p = idx >> 5, c = idx & 31;
        pL[p * 36 + c] = bf2f(pre[gp0 * 32 + idx]);
    }
    __syncthreads();
    const int og = tid >> 6, px = tid & 63;
    float4 pv[8];
#pragma unroll
    for (int c4 = 0; c4 < 8; ++c4)
        pv[c4] = *(const float4*)&pL[px * 36 + c4 * 4];
#pragma unroll
    for (int g = 0; g < 4; ++g) {
        float acc[16];
#pragma unroll
        for (int jj = 0; jj < 16; ++jj) acc[jj] = bfb[og * 64 + g * 16 + jj];
#pragma unroll
        for (int c4 = 0; c4 < 8; ++c4) {
            const float4 xv = pv[c4];
#pragma unroll
            for (int jj = 0; jj < 16; ++jj) {
                const float4 wv = *(const float4*)&wfL[(og * 64 + g * 16 + jj) * 32 + c4 * 4];
                acc[jj] += wv.x * xv.x + wv.y * xv.y + wv.z * xv.z + wv.w * xv.w;
            }
        }
#pragma unroll
        for (int jj = 0; jj < 16; ++jj) {
            const int o = og * 64 + g * 16 + jj;
            const int ga = ((b << 8) + o) * 4096 + p0 + px;
            out[ga] = x[ga] + A[o] * acc[jj] + S[o];
        }
    }
}

extern "C" void kernel_launch(void* const* d_in, const int* in_sizes, int n_in,
                              void* d_out, int out_size, void* d_ws, size_t ws_size,
                              hipStream_t stream)
{
    (void)in_sizes; (void)n_in; (void)out_size; (void)ws_size;
    float* out = (float*)d_out;
    char* ws = (char*)d_ws;

    const float* x      = (const float*)d_in[0];
    const float* vessel = (const float*)d_in[1];
    const float* wk     = (const float*)d_in[2];
    const float* bk     = (const float*)d_in[3];
    const float* wq     = (const float*)d_in[4];
    const float* bq     = (const float*)d_in[5];
    const float* wx     = (const float*)d_in[6];
    const float* bx     = (const float*)d_in[7];
    const float* wf     = (const float*)d_in[8];
    const float* bfb    = (const float*)d_in[9];
    const float* gamma  = (const float*)d_in[10];
    const float* beta   = (const float*)d_in[11];

    bf16* km  = (bf16*)(ws);                    // 1 MB
    bf16* qm  = (bf16*)(ws + 1048576);          // 1 MB
    bf16* xm  = (bf16*)(ws + 2097152);          // 1 MB
    bf16* pre = (bf16*)(ws + 3145728);          // 1 MB
    float* partials = (float*)(ws + 4194304);   // 270336 B
    float* Abuf     = (float*)(ws + 4464640);
    float* Sbuf     = (float*)(ws + 4465664);

    k_proj <<<512, 256, 0, stream>>>(x, vessel, wk, bk, wq, bq, wx, bx,
                                     km, qm, xm);
    k_attn <<<256, 256, 0, stream>>>(km, qm, xm, pre);
    k_cov  <<< 64, 256, 0, stream>>>(pre, partials);
    k_stats<<<  1, 256, 0, stream>>>(partials, wf, bfb, gamma, beta, Abuf, Sbuf);
    k_out  <<<256, 256, 0, stream>>>(pre, wf, bfb, x, Abuf, Sbuf, out);
}

// Round 11
// 231.518 us; speedup vs baseline: 1.3945x; 1.3945x over previous
//
#include <hip/hip_runtime.h>
#include <hip/hip_bf16.h>

typedef __hip_bfloat16 bf16;
typedef unsigned short u16;
typedef unsigned int u32;

__device__ __forceinline__ float bf2f(bf16 v) { return __bfloat162float(v); }
__device__ __forceinline__ float us2f(u16 u) {
    union { u32 i; float f; } c; c.i = ((u32)u) << 16; return c.f;
}
// unpack 8 bf16 (packed in uint4) -> 8 floats
__device__ __forceinline__ void up8(const uint4 v, float* f) {
    f[0] = us2f((u16)(v.x & 0xffff)); f[1] = us2f((u16)(v.x >> 16));
    f[2] = us2f((u16)(v.y & 0xffff)); f[3] = us2f((u16)(v.y >> 16));
    f[4] = us2f((u16)(v.z & 0xffff)); f[5] = us2f((u16)(v.z >> 16));
    f[6] = us2f((u16)(v.w & 0xffff)); f[7] = us2f((u16)(v.w >> 16));
}

// ---------------------------------------------------------------------------
// K1: km/qm/xm = conv1x1(x,{wk,wq,wx}) (+bias, km*=vessel), bf16 out.
// 512 blocks x 32 px (>=2 blocks/CU), 256 thr = 8 og x 12 outputs.
// NO forced min-waves: r10's __launch_bounds__(256,4) squeezed VGPR to 64
// -> accumulator spills -> 400 MB scratch HBM traffic (measured). xs pad 68
// (4-way LDS conflicts, benign per r9's 393K count). LDS 33.3 KB.
// ---------------------------------------------------------------------------
__global__ __launch_bounds__(256) void k_proj(
    const float* __restrict__ x, const float* __restrict__ vessel,
    const float* __restrict__ wk, const float* __restrict__ bk,
    const float* __restrict__ wq, const float* __restrict__ bq,
    const float* __restrict__ wx, const float* __restrict__ bx,
    bf16* __restrict__ km, bf16* __restrict__ qm, bf16* __restrict__ xm)
{
    __shared__ float xs[32 * 68];    // [px][cc] pad 68 (8704 B)
    __shared__ float wch[96 * 64];   // [o][cc]  (24576 B)
    const int tid = threadIdx.x;
    const int og = tid >> 5, px = tid & 31;      // 8 og x 32 px
    const int b = blockIdx.x >> 7;
    const int p0 = (blockIdx.x & 127) * 32;

    float acc[12];
#pragma unroll
    for (int j = 0; j < 12; ++j) {
        const int o = og * 12 + j;
        const float* bs = (o < 32) ? bk : ((o < 64) ? bq : bx);
        acc[j] = bs[o & 31];
    }
    for (int c0 = 0; c0 < 256; c0 += 64) {
        __syncthreads();
#pragma unroll
        for (int i = 0; i < 24; ++i) {           // 96 o x 64 cc weights
            const int idx = tid + i * 256;
            const int o = idx >> 6, cc = idx & 63;
            const float* wp = (o < 32) ? wk : ((o < 64) ? wq : wx);
            wch[o * 64 + cc] = wp[(o & 31) * 256 + c0 + cc];
        }
#pragma unroll
        for (int i = 0; i < 8; ++i) {            // 64 cc x 32 px
            const int idx = tid + i * 256;
            const int cc = idx >> 5, pl = idx & 31;
            xs[pl * 68 + cc] = x[(b * 256 + c0 + cc) * 4096 + p0 + pl];
        }
        __syncthreads();
#pragma unroll
        for (int c4 = 0; c4 < 16; ++c4) {
            const float4 xv = *(const float4*)&xs[px * 68 + c4 * 4];
#pragma unroll
            for (int j = 0; j < 12; ++j) {
                const float4 wv = *(const float4*)&wch[(og * 12 + j) * 64 + c4 * 4];
                acc[j] += wv.x * xv.x + wv.y * xv.y + wv.z * xv.z + wv.w * xv.w;
            }
        }
    }
    const float v = vessel[b * 4096 + p0 + px];
    const int gp = (b * 4096 + p0 + px) * 32;
#pragma unroll
    for (int j = 0; j < 12; ++j) {
        const int o = og * 12 + j;
        const int ch = o & 31;
        if (o < 32)      km[gp + ch] = __float2bfloat16(acc[j] * v);
        else if (o < 64) qm[gp + ch] = __float2bfloat16(acc[j]);
        else             xm[gp + ch] = __float2bfloat16(acc[j]);
    }
}

// ---------------------------------------------------------------------------
// K2: 4-scale local attention, nested-window fusion (r10 version, kept:
// uint4 LDS reads + cached pass-1 exponentials). OOB halo = 0 => s = 0
// matches reference zero-padding in the softmax denominator. LDS 61 KB.
// ---------------------------------------------------------------------------
__global__ __launch_bounds__(256) void k_attn(
    const bf16* __restrict__ km, const bf16* __restrict__ qm,
    const bf16* __restrict__ xm, bf16* __restrict__ pre)
{
    __shared__ u16 kT[256 * 40];     // 20480 B
    __shared__ u16 xT[256 * 40];     // 20480 B
    __shared__ float sc[64 * 84];    // 21504 B
    const int tid = threadIdx.x;
    const int b = blockIdx.x >> 6;
    const int tile = blockIdx.x & 63;
    const int h0 = (tile >> 3) * 8, w0 = (tile & 7) * 8;
    const u16* uk = (const u16*)km;
    const u16* ux = (const u16*)xm;

    const uint4 z4 = {0u, 0u, 0u, 0u};
#pragma unroll
    for (int i = 0; i < 4; ++i) {
        const int idx4 = tid + i * 256;          // 0..1023 uint4 groups
        const int pos = idx4 >> 2, c8 = idx4 & 3;
        const int gh = h0 - 4 + (pos >> 4), gw = w0 - 4 + (pos & 15);
        uint4 kv = z4, xv = z4;
        if (gh >= 0 && gh < 64 && gw >= 0 && gw < 64) {
            const int g = ((b << 12) + (gh << 6) + gw) * 32 + c8 * 8;
            kv = *(const uint4*)&uk[g];
            xv = *(const uint4*)&ux[g];
        }
        *(uint4*)&kT[pos * 40 + c8 * 8] = kv;
        *(uint4*)&xT[pos * 40 + c8 * 8] = xv;
    }
    const int px = tid >> 2, cg = tid & 3;
    const int py = px >> 3, pxx = px & 7;
    const int gp = ((b << 12) + ((h0 + py) << 6) + (w0 + pxx)) * 32;
    float q[8];
    up8(*(const uint4*)&((const u16*)qm)[gp + cg * 8], q);
    __syncthreads();

    // pass 1: dots over the 9x9 superset; e cached in sc; ring sums
    float Z3 = 0.f, Z5 = 0.f, Z7 = 0.f, Z9 = 0.f;
    for (int j = 0; j < 81; ++j) {
        const int jd = j / 9;
        const int dy = jd - 4, dx = j - jd * 9 - 4;
        const int pos = (py + 4 + dy) * 16 + (pxx + 4 + dx);
        float kf[8];
        up8(*(const uint4*)&kT[pos * 40 + cg * 8], kf);
        float s = kf[0]*q[0] + kf[1]*q[1] + kf[2]*q[2] + kf[3]*q[3]
                + kf[4]*q[4] + kf[5]*q[5] + kf[6]*q[6] + kf[7]*q[7];
        s += __shfl_xor(s, 1);
        s += __shfl_xor(s, 2);
        const float e = __expf(s);
        if (cg == 0) sc[px * 84 + j] = e;
        const int ady = dy < 0 ? -dy : dy, adx = dx < 0 ? -dx : dx;
        const int r = ady > adx ? ady : adx;
        if (r <= 1) Z3 += e;
        if (r <= 2) Z5 += e;
        if (r <= 3) Z7 += e;
        Z9 += e;
    }
    const float iZ3 = 1.f / Z3, iZ5 = 1.f / Z5, iZ7 = 1.f / Z7, iZ9 = 1.f / Z9;
    __syncthreads();

    // pass 2: weighted value accumulation from cached e
    float acc[8];
#pragma unroll
    for (int i = 0; i < 8; ++i) acc[i] = 0.f;
    for (int j = 0; j < 81; ++j) {
        const int jd = j / 9;
        const int dy = jd - 4, dx = j - jd * 9 - 4;
        const int pos = (py + 4 + dy) * 16 + (pxx + 4 + dx);
        const float e = sc[px * 84 + j];
        const int ady = dy < 0 ? -dy : dy, adx = dx < 0 ? -dx : dx;
        const int r = ady > adx ? ady : adx;
        float coef = iZ9;
        if (r <= 1) coef += iZ3;
        if (r <= 2) coef += iZ5;
        if (r <= 3) coef += iZ7;
        const float w = e * coef;
        float xf[8];
        up8(*(const uint4*)&xT[pos * 40 + cg * 8], xf);
#pragma unroll
        for (int i = 0; i < 8; ++i) acc[i] += w * xf[i];
    }
#pragma unroll
    for (int i = 0; i < 8; ++i) pre[gp + cg * 8 + i] = __float2bfloat16(acc[i]);
}

// ---------------------------------------------------------------------------
// K2b: partial S2 = pre^T pre (32x32) + S1 = sum(pre), 256 px/blk
// ---------------------------------------------------------------------------
__global__ __launch_bounds__(256) void k_cov(
    const bf16* __restrict__ pre, float* __restrict__ partials)
{
    __shared__ float t[256 * 32];
    const int tid = threadIdx.x;
    const int p0 = blockIdx.x * 256;
    for (int i = 0; i < 32; ++i) {
        const int idx = tid + i * 256;
        t[idx] = bf2f(pre[p0 * 32 + idx]);
    }
    __syncthreads();
    const int i0 = tid >> 3, j0 = (tid & 7) * 4;
    float4 a = {0.f, 0.f, 0.f, 0.f};
    for (int p = 0; p < 256; ++p) {
        const float vi = t[p * 32 + i0];
        const float4 vj = *(const float4*)&t[p * 32 + j0];
        a.x += vi * vj.x; a.y += vi * vj.y; a.z += vi * vj.z; a.w += vi * vj.w;
    }
    *(float4*)&partials[blockIdx.x * 1056 + i0 * 32 + j0] = a;
    if (tid < 32) {
        float s = 0.f;
        for (int p = 0; p < 256; ++p) s += t[p * 32 + tid];
        partials[blockIdx.x * 1056 + 1024 + tid] = s;
    }
}

// ---------------------------------------------------------------------------
// K2c: BN constants. meanY[o]=wf_o.mu+bf[o]; var=wf_o S2 wf_o^T/N-(wf_o.mu)^2
// A = gamma*rsqrt(var+eps); S = beta - A*meanY (k_out adds bf into y).
// ---------------------------------------------------------------------------
__global__ __launch_bounds__(256) void k_stats(
    const float* __restrict__ partials, const float* __restrict__ wf,
    const float* __restrict__ bfb, const float* __restrict__ gamma,
    const float* __restrict__ beta,
    float* __restrict__ Aout, float* __restrict__ Sout)
{
    __shared__ float cov[1024];
    __shared__ float mu[32];
    const int tid = threadIdx.x;
    float4 a = {0.f, 0.f, 0.f, 0.f};
    for (int blk = 0; blk < 64; ++blk) {
        const float4 p = *(const float4*)&partials[blk * 1056 + tid * 4];
        a.x += p.x; a.y += p.y; a.z += p.z; a.w += p.w;
    }
    *(float4*)&cov[tid * 4] = a;
    if (tid < 32) {
        float s = 0.f;
        for (int blk = 0; blk < 64; ++blk) s += partials[blk * 1056 + 1024 + tid];
        mu[tid] = s * (1.f / 16384.f);
    }
    __syncthreads();
    float wo[32];
#pragma unroll
    for (int c = 0; c < 32; ++c) wo[c] = wf[tid * 32 + c];
    float mv = 0.f;
#pragma unroll
    for (int c = 0; c < 32; ++c) mv += wo[c] * mu[c];
    float qacc = 0.f;
    for (int i2 = 0; i2 < 32; ++i2) {
        float t = 0.f;
#pragma unroll
        for (int j2 = 0; j2 < 32; ++j2) t += wo[j2] * cov[i2 * 32 + j2];
        qacc += wo[i2] * t;
    }
    const float var = qacc * (1.f / 16384.f) - mv * mv;
    const float A = gamma[tid] * rsqrtf(var + 1e-5f);
    Aout[tid] = A;
    Sout[tid] = beta[tid] - A * (mv + bfb[tid]);
}

// ---------------------------------------------------------------------------
// K3: out = x + A*(wf.pre + bf) + S, f32 out. Register-blocked (r9 PASS).
// ---------------------------------------------------------------------------
__global__ __launch_bounds__(256) void k_out(
    const bf16* __restrict__ pre, const float* __restrict__ wf,
    const float* __restrict__ bfb, const float* __restrict__ x,
    const float* __restrict__ A, const float* __restrict__ S,
    float* __restrict__ out)
{
    __shared__ float wfL[256 * 32];  // 32768 B
    __shared__ float pL[64 * 36];    //  9216 B
    const int tid = threadIdx.x;
    const int gp0 = blockIdx.x * 64;
    const int b = gp0 >> 12, p0 = gp0 & 4095;
#pragma unroll
    for (int i = 0; i < 8; ++i) {
        const int idx4 = tid + i * 256;
        *(float4*)&wfL[idx4 * 4] = *(const float4*)&wf[idx4 * 4];
    }
    for (int i = 0; i < 8; ++i) {
        const int idx = tid + i * 256;
        const int p = idx >> 5, c = idx & 31;
        pL[p * 36 + c] = bf2f(pre[gp0 * 32 + idx]);
    }
    __syncthreads();
    const int og = tid >> 6, px = tid & 63;
    float4 pv[8];
#pragma unroll
    for (int c4 = 0; c4 < 8; ++c4)
        pv[c4] = *(const float4*)&pL[px * 36 + c4 * 4];
#pragma unroll
    for (int g = 0; g < 4; ++g) {
        float acc[16];
#pragma unroll
        for (int jj = 0; jj < 16; ++jj) acc[jj] = bfb[og * 64 + g * 16 + jj];
#pragma unroll
        for (int c4 = 0; c4 < 8; ++c4) {
            const float4 xv = pv[c4];
#pragma unroll
            for (int jj = 0; jj < 16; ++jj) {
                const float4 wv = *(const float4*)&wfL[(og * 64 + g * 16 + jj) * 32 + c4 * 4];
                acc[jj] += wv.x * xv.x + wv.y * xv.y + wv.z * xv.z + wv.w * xv.w;
            }
        }
#pragma unroll
        for (int jj = 0; jj < 16; ++jj) {
            const int o = og * 64 + g * 16 + jj;
            const int ga = ((b << 8) + o) * 4096 + p0 + px;
            out[ga] = x[ga] + A[o] * acc[jj] + S[o];
        }
    }
}

extern "C" void kernel_launch(void* const* d_in, const int* in_sizes, int n_in,
                              void* d_out, int out_size, void* d_ws, size_t ws_size,
                              hipStream_t stream)
{
    (void)in_sizes; (void)n_in; (void)out_size; (void)ws_size;
    float* out = (float*)d_out;
    char* ws = (char*)d_ws;

    const float* x      = (const float*)d_in[0];
    const float* vessel = (const float*)d_in[1];
    const float* wk     = (const float*)d_in[2];
    const float* bk     = (const float*)d_in[3];
    const float* wq     = (const float*)d_in[4];
    const float* bq     = (const float*)d_in[5];
    const float* wx     = (const float*)d_in[6];
    const float* bx     = (const float*)d_in[7];
    const float* wf     = (const float*)d_in[8];
    const float* bfb    = (const float*)d_in[9];
    const float* gamma  = (const float*)d_in[10];
    const float* beta   = (const float*)d_in[11];

    bf16* km  = (bf16*)(ws);                    // 1 MB
    bf16* qm  = (bf16*)(ws + 1048576);          // 1 MB
    bf16* xm  = (bf16*)(ws + 2097152);          // 1 MB
    bf16* pre = (bf16*)(ws + 3145728);          // 1 MB
    float* partials = (float*)(ws + 4194304);   // 270336 B
    float* Abuf     = (float*)(ws + 4464640);
    float* Sbuf     = (float*)(ws + 4465664);

    k_proj <<<512, 256, 0, stream>>>(x, vessel, wk, bk, wq, bq, wx, bx,
                                     km, qm, xm);
    k_attn <<<256, 256, 0, stream>>>(km, qm, xm, pre);
    k_cov  <<< 64, 256, 0, stream>>>(pre, partials);
    k_stats<<<  1, 256, 0, stream>>>(partials, wf, bfb, gamma, beta, Abuf, Sbuf);
    k_out  <<<256, 256, 0, stream>>>(pre, wf, bfb, x, Abuf, Sbuf, out);
}

// Round 12
// 160.870 us; speedup vs baseline: 2.0069x; 1.4392x over previous
//
#include <hip/hip_runtime.h>
#include <hip/hip_bf16.h>

typedef __hip_bfloat16 bf16;
typedef unsigned short u16;
typedef unsigned int u32;

typedef __bf16 bf16x8 __attribute__((ext_vector_type(8)));
typedef float f32x4 __attribute__((ext_vector_type(4)));

__device__ __forceinline__ float bf2f(bf16 v) { return __bfloat162float(v); }
__device__ __forceinline__ float us2f(u16 u) {
    union { u32 i; float f; } c; c.i = ((u32)u) << 16; return c.f;
}
__device__ __forceinline__ u16 f2u(float f) {
    union { bf16 b; u16 u; } c; c.b = __float2bfloat16(f); return c.u;
}
// unpack 8 bf16 (packed in uint4) -> 8 floats
__device__ __forceinline__ void up8(const uint4 v, float* f) {
    f[0] = us2f((u16)(v.x & 0xffff)); f[1] = us2f((u16)(v.x >> 16));
    f[2] = us2f((u16)(v.y & 0xffff)); f[3] = us2f((u16)(v.y >> 16));
    f[4] = us2f((u16)(v.z & 0xffff)); f[5] = us2f((u16)(v.z >> 16));
    f[6] = us2f((u16)(v.w & 0xffff)); f[7] = us2f((u16)(v.w >> 16));
}

// ---------------------------------------------------------------------------
// K1 (MFMA GEMM): km/qm/xm = conv1x1(x,{wk,wq,wx}) (+bias, km*=vessel).
// M=64 px x N=48 outs x K=256 per block; 4 waves, each: row-tile w,
// 3 col-tiles, 8 x mfma_f32_16x16x32_bf16 per tile. A[m=lane&15][k=quad*8+j],
// B[n=lane&15][k=quad*8+j] (W is [o][ch] = B^T layout), C col=lane&15,
// row=quad*4+reg (verified m89/m91 mapping). LDS 59.1 KB, one barrier.
// Grid = 256 px-tiles x 2 N-halves = 512.
// ---------------------------------------------------------------------------
__global__ __launch_bounds__(256) void k_proj(
    const float* __restrict__ x, const float* __restrict__ vessel,
    const float* __restrict__ wk, const float* __restrict__ bk,
    const float* __restrict__ wq, const float* __restrict__ bq,
    const float* __restrict__ wx, const float* __restrict__ bx,
    bf16* __restrict__ km, bf16* __restrict__ qm, bf16* __restrict__ xm)
{
    __shared__ u16 xs[64 * 264];     // [px][ch] bf16, stride 264 (33792 B)
    __shared__ u16 wsh[48 * 264];    // [o_local][ch] bf16 (25344 B)
    const int tid = threadIdx.x;
    const int bid = blockIdx.x;
    const int nh = bid & 1;                  // N-half: outputs nh*48..+47
    const int pt = bid >> 1;
    const int b  = pt >> 6;
    const int p0 = (pt & 63) * 64;

    // stage x tile: 64 px x 256 ch -> bf16 LDS
#pragma unroll
    for (int i = 0; i < 16; ++i) {
        const int idx4 = tid + i * 256;      // 0..4095
        const int ch = idx4 >> 4;            // 0..255
        const int px4 = (idx4 & 15) * 4;     // 0,4,..,60
        const float4 v = *(const float4*)&x[(b * 256 + ch) * 4096 + p0 + px4];
        xs[(px4 + 0) * 264 + ch] = f2u(v.x);
        xs[(px4 + 1) * 264 + ch] = f2u(v.y);
        xs[(px4 + 2) * 264 + ch] = f2u(v.z);
        xs[(px4 + 3) * 264 + ch] = f2u(v.w);
    }
    // stage W half: 48 outputs x 256 ch -> bf16 LDS
#pragma unroll
    for (int i = 0; i < 12; ++i) {
        const int idx4 = tid + i * 256;      // 0..3071
        const int o = idx4 >> 6;             // 0..47 local
        const int ch4 = (idx4 & 63) * 4;
        const int go = nh * 48 + o;
        const float* wp = (go < 32) ? wk : ((go < 64) ? wq : wx);
        const float4 v = *(const float4*)&wp[(go & 31) * 256 + ch4];
        wsh[o * 264 + ch4 + 0] = f2u(v.x);
        wsh[o * 264 + ch4 + 1] = f2u(v.y);
        wsh[o * 264 + ch4 + 2] = f2u(v.z);
        wsh[o * 264 + ch4 + 3] = f2u(v.w);
    }
    __syncthreads();

    const int w = tid >> 6;                  // wave = row-tile 0..3
    const int lane = tid & 63;
    const int lm = lane & 15, quad = lane >> 4;

    f32x4 acc0 = {0.f, 0.f, 0.f, 0.f};
    f32x4 acc1 = {0.f, 0.f, 0.f, 0.f};
    f32x4 acc2 = {0.f, 0.f, 0.f, 0.f};
#pragma unroll
    for (int kk = 0; kk < 8; ++kk) {
        const int k0 = kk * 32 + quad * 8;
        const bf16x8 a  = *(const bf16x8*)&xs[(w * 16 + lm) * 264 + k0];
        const bf16x8 b0 = *(const bf16x8*)&wsh[(0 + lm) * 264 + k0];
        const bf16x8 b1 = *(const bf16x8*)&wsh[(16 + lm) * 264 + k0];
        const bf16x8 b2 = *(const bf16x8*)&wsh[(32 + lm) * 264 + k0];
        acc0 = __builtin_amdgcn_mfma_f32_16x16x32_bf16(a, b0, acc0, 0, 0, 0);
        acc1 = __builtin_amdgcn_mfma_f32_16x16x32_bf16(a, b1, acc1, 0, 0, 0);
        acc2 = __builtin_amdgcn_mfma_f32_16x16x32_bf16(a, b2, acc2, 0, 0, 0);
    }
#pragma unroll
    for (int t = 0; t < 3; ++t) {
        const f32x4 acc = (t == 0) ? acc0 : ((t == 1) ? acc1 : acc2);
        const int go = nh * 48 + t * 16 + lm;        // global output 0..95
        const float* bs = (go < 32) ? bk : ((go < 64) ? bq : bx);
        const float bias = bs[go & 31];
        bf16* dst = (go < 32) ? km : ((go < 64) ? qm : xm);
#pragma unroll
        for (int rg = 0; rg < 4; ++rg) {
            const int px = p0 + w * 16 + quad * 4 + rg;    // px within b
            float vv = acc[rg] + bias;
            if (go < 32) vv *= vessel[b * 4096 + px];
            dst[(b * 4096 + px) * 32 + (go & 31)] = __float2bfloat16(vv);
        }
    }
}

// ---------------------------------------------------------------------------
// K2: 4-scale local attention, nested-window fusion (r11 version, unchanged)
// ---------------------------------------------------------------------------
__global__ __launch_bounds__(256) void k_attn(
    const bf16* __restrict__ km, const bf16* __restrict__ qm,
    const bf16* __restrict__ xm, bf16* __restrict__ pre)
{
    __shared__ u16 kT[256 * 40];
    __shared__ u16 xT[256 * 40];
    __shared__ float sc[64 * 84];
    const int tid = threadIdx.x;
    const int b = blockIdx.x >> 6;
    const int tile = blockIdx.x & 63;
    const int h0 = (tile >> 3) * 8, w0 = (tile & 7) * 8;
    const u16* uk = (const u16*)km;
    const u16* ux = (const u16*)xm;

    const uint4 z4 = {0u, 0u, 0u, 0u};
#pragma unroll
    for (int i = 0; i < 4; ++i) {
        const int idx4 = tid + i * 256;
        const int pos = idx4 >> 2, c8 = idx4 & 3;
        const int gh = h0 - 4 + (pos >> 4), gw = w0 - 4 + (pos & 15);
        uint4 kv = z4, xv = z4;
        if (gh >= 0 && gh < 64 && gw >= 0 && gw < 64) {
            const int g = ((b << 12) + (gh << 6) + gw) * 32 + c8 * 8;
            kv = *(const uint4*)&uk[g];
            xv = *(const uint4*)&ux[g];
        }
        *(uint4*)&kT[pos * 40 + c8 * 8] = kv;
        *(uint4*)&xT[pos * 40 + c8 * 8] = xv;
    }
    const int px = tid >> 2, cg = tid & 3;
    const int py = px >> 3, pxx = px & 7;
    const int gp = ((b << 12) + ((h0 + py) << 6) + (w0 + pxx)) * 32;
    float q[8];
    up8(*(const uint4*)&((const u16*)qm)[gp + cg * 8], q);
    __syncthreads();

    float Z3 = 0.f, Z5 = 0.f, Z7 = 0.f, Z9 = 0.f;
    for (int j = 0; j < 81; ++j) {
        const int jd = j / 9;
        const int dy = jd - 4, dx = j - jd * 9 - 4;
        const int pos = (py + 4 + dy) * 16 + (pxx + 4 + dx);
        float kf[8];
        up8(*(const uint4*)&kT[pos * 40 + cg * 8], kf);
        float s = kf[0]*q[0] + kf[1]*q[1] + kf[2]*q[2] + kf[3]*q[3]
                + kf[4]*q[4] + kf[5]*q[5] + kf[6]*q[6] + kf[7]*q[7];
        s += __shfl_xor(s, 1);
        s += __shfl_xor(s, 2);
        const float e = __expf(s);
        if (cg == 0) sc[px * 84 + j] = e;
        const int ady = dy < 0 ? -dy : dy, adx = dx < 0 ? -dx : dx;
        const int r = ady > adx ? ady : adx;
        if (r <= 1) Z3 += e;
        if (r <= 2) Z5 += e;
        if (r <= 3) Z7 += e;
        Z9 += e;
    }
    const float iZ3 = 1.f / Z3, iZ5 = 1.f / Z5, iZ7 = 1.f / Z7, iZ9 = 1.f / Z9;
    __syncthreads();

    float acc[8];
#pragma unroll
    for (int i = 0; i < 8; ++i) acc[i] = 0.f;
    for (int j = 0; j < 81; ++j) {
        const int jd = j / 9;
        const int dy = jd - 4, dx = j - jd * 9 - 4;
        const int pos = (py + 4 + dy) * 16 + (pxx + 4 + dx);
        const float e = sc[px * 84 + j];
        const int ady = dy < 0 ? -dy : dy, adx = dx < 0 ? -dx : dx;
        const int r = ady > adx ? ady : adx;
        float coef = iZ9;
        if (r <= 1) coef += iZ3;
        if (r <= 2) coef += iZ5;
        if (r <= 3) coef += iZ7;
        const float w = e * coef;
        float xf[8];
        up8(*(const uint4*)&xT[pos * 40 + cg * 8], xf);
#pragma unroll
        for (int i = 0; i < 8; ++i) acc[i] += w * xf[i];
    }
#pragma unroll
    for (int i = 0; i < 8; ++i) pre[gp + cg * 8 + i] = __float2bfloat16(acc[i]);
}

// ---------------------------------------------------------------------------
// K2b: partial S2 = pre^T pre (32x32) + S1 = sum(pre), 256 px/blk (unchanged)
// ---------------------------------------------------------------------------
__global__ __launch_bounds__(256) void k_cov(
    const bf16* __restrict__ pre, float* __restrict__ partials)
{
    __shared__ float t[256 * 32];
    const int tid = threadIdx.x;
    const int p0 = blockIdx.x * 256;
    for (int i = 0; i < 32; ++i) {
        const int idx = tid + i * 256;
        t[idx] = bf2f(pre[p0 * 32 + idx]);
    }
    __syncthreads();
    const int i0 = tid >> 3, j0 = (tid & 7) * 4;
    float4 a = {0.f, 0.f, 0.f, 0.f};
    for (int p = 0; p < 256; ++p) {
        const float vi = t[p * 32 + i0];
        const float4 vj = *(const float4*)&t[p * 32 + j0];
        a.x += vi * vj.x; a.y += vi * vj.y; a.z += vi * vj.z; a.w += vi * vj.w;
    }
    *(float4*)&partials[blockIdx.x * 1056 + i0 * 32 + j0] = a;
    if (tid < 32) {
        float s = 0.f;
        for (int p = 0; p < 256; ++p) s += t[p * 32 + tid];
        partials[blockIdx.x * 1056 + 1024 + tid] = s;
    }
}

// ---------------------------------------------------------------------------
// K2c: BN constants (unchanged)
// ---------------------------------------------------------------------------
__global__ __launch_bounds__(256) void k_stats(
    const float* __restrict__ partials, const float* __restrict__ wf,
    const float* __restrict__ bfb, const float* __restrict__ gamma,
    const float* __restrict__ beta,
    float* __restrict__ Aout, float* __restrict__ Sout)
{
    __shared__ float cov[1024];
    __shared__ float mu[32];
    const int tid = threadIdx.x;
    float4 a = {0.f, 0.f, 0.f, 0.f};
    for (int blk = 0; blk < 64; ++blk) {
        const float4 p = *(const float4*)&partials[blk * 1056 + tid * 4];
        a.x += p.x; a.y += p.y; a.z += p.z; a.w += p.w;
    }
    *(float4*)&cov[tid * 4] = a;
    if (tid < 32) {
        float s = 0.f;
        for (int blk = 0; blk < 64; ++blk) s += partials[blk * 1056 + 1024 + tid];
        mu[tid] = s * (1.f / 16384.f);
    }
    __syncthreads();
    float wo[32];
#pragma unroll
    for (int c = 0; c < 32; ++c) wo[c] = wf[tid * 32 + c];
    float mv = 0.f;
#pragma unroll
    for (int c = 0; c < 32; ++c) mv += wo[c] * mu[c];
    float qacc = 0.f;
    for (int i2 = 0; i2 < 32; ++i2) {
        float t = 0.f;
#pragma unroll
        for (int j2 = 0; j2 < 32; ++j2) t += wo[j2] * cov[i2 * 32 + j2];
        qacc += wo[i2] * t;
    }
    const float var = qacc * (1.f / 16384.f) - mv * mv;
    const float A = gamma[tid] * rsqrtf(var + 1e-5f);
    Aout[tid] = A;
    Sout[tid] = beta[tid] - A * (mv + bfb[tid]);
}

// ---------------------------------------------------------------------------
// K3: out = x + A*(wf.pre + bf) + S, f32 out (unchanged)
// ---------------------------------------------------------------------------
__global__ __launch_bounds__(256) void k_out(
    const bf16* __restrict__ pre, const float* __restrict__ wf,
    const float* __restrict__ bfb, const float* __restrict__ x,
    const float* __restrict__ A, const float* __restrict__ S,
    float* __restrict__ out)
{
    __shared__ float wfL[256 * 32];
    __shared__ float pL[64 * 36];
    const int tid = threadIdx.x;
    const int gp0 = blockIdx.x * 64;
    const int b = gp0 >> 12, p0 = gp0 & 4095;
#pragma unroll
    for (int i = 0; i < 8; ++i) {
        const int idx4 = tid + i * 256;
        *(float4*)&wfL[idx4 * 4] = *(const float4*)&wf[idx4 * 4];
    }
    for (int i = 0; i < 8; ++i) {
        const int idx = tid + i * 256;
        const int p = idx >> 5, c = idx & 31;
        pL[p * 36 + c] = bf2f(pre[gp0 * 32 + idx]);
    }
    __syncthreads();
    const int og = tid >> 6, px = tid & 63;
    float4 pv[8];
#pragma unroll
    for (int c4 = 0; c4 < 8; ++c4)
        pv[c4] = *(const float4*)&pL[px * 36 + c4 * 4];
#pragma unroll
    for (int g = 0; g < 4; ++g) {
        float acc[16];
#pragma unroll
        for (int jj = 0; jj < 16; ++jj) acc[jj] = bfb[og * 64 + g * 16 + jj];
#pragma unroll
        for (int c4 = 0; c4 < 8; ++c4) {
            const float4 xv = pv[c4];
#pragma unroll
            for (int jj = 0; jj < 16; ++jj) {
                const float4 wv = *(const float4*)&wfL[(og * 64 + g * 16 + jj) * 32 + c4 * 4];
                acc[jj] += wv.x * xv.x + wv.y * xv.y + wv.z * xv.z + wv.w * xv.w;
            }
        }
#pragma unroll
        for (int jj = 0; jj < 16; ++jj) {
            const int o = og * 64 + g * 16 + jj;
            const int ga = ((b << 8) + o) * 4096 + p0 + px;
            out[ga] = x[ga] + A[o] * acc[jj] + S[o];
        }
    }
}

extern "C" void kernel_launch(void* const* d_in, const int* in_sizes, int n_in,
                              void* d_out, int out_size, void* d_ws, size_t ws_size,
                              hipStream_t stream)
{
    (void)in_sizes; (void)n_in; (void)out_size; (void)ws_size;
    float* out = (float*)d_out;
    char* ws = (char*)d_ws;

    const float* x      = (const float*)d_in[0];
    const float* vessel = (const float*)d_in[1];
    const float* wk     = (const float*)d_in[2];
    const float* bk     = (const float*)d_in[3];
    const float* wq     = (const float*)d_in[4];
    const float* bq     = (const float*)d_in[5];
    const float* wx     = (const float*)d_in[6];
    const float* bx     = (const float*)d_in[7];
    const float* wf     = (const float*)d_in[8];
    const float* bfb    = (const float*)d_in[9];
    const float* gamma  = (const float*)d_in[10];
    const float* beta   = (const float*)d_in[11];

    bf16* km  = (bf16*)(ws);                    // 1 MB
    bf16* qm  = (bf16*)(ws + 1048576);          // 1 MB
    bf16* xm  = (bf16*)(ws + 2097152);          // 1 MB
    bf16* pre = (bf16*)(ws + 3145728);          // 1 MB
    float* partials = (float*)(ws + 4194304);   // 270336 B
    float* Abuf     = (float*)(ws + 4464640);
    float* Sbuf     = (float*)(ws + 4465664);

    k_proj <<<512, 256, 0, stream>>>(x, vessel, wk, bk, wq, bq, wx, bx,
                                     km, qm, xm);
    k_attn <<<256, 256, 0, stream>>>(km, qm, xm, pre);
    k_cov  <<< 64, 256, 0, stream>>>(pre, partials);
    k_stats<<<  1, 256, 0, stream>>>(partials, wf, bfb, gamma, beta, Abuf, Sbuf);
    k_out  <<<256, 256, 0, stream>>>(pre, wf, bfb, x, Abuf, Sbuf, out);
}

// Round 13
// 138.202 us; speedup vs baseline: 2.3361x; 1.1640x over previous
//
#include <hip/hip_runtime.h>
#include <hip/hip_bf16.h>

typedef __hip_bfloat16 bf16;
typedef unsigned short u16;
typedef unsigned int u32;

typedef __bf16 bf16x8 __attribute__((ext_vector_type(8)));
typedef float f32x4 __attribute__((ext_vector_type(4)));

__device__ __forceinline__ float bf2f(bf16 v) { return __bfloat162float(v); }
__device__ __forceinline__ float us2f(u16 u) {
    union { u32 i; float f; } c; c.i = ((u32)u) << 16; return c.f;
}
__device__ __forceinline__ u16 f2u(float f) {
    union { bf16 b; u16 u; } c; c.b = __float2bfloat16(f); return c.u;
}
__device__ __forceinline__ void up8(const uint4 v, float* f) {
    f[0] = us2f((u16)(v.x & 0xffff)); f[1] = us2f((u16)(v.x >> 16));
    f[2] = us2f((u16)(v.y & 0xffff)); f[3] = us2f((u16)(v.y >> 16));
    f[4] = us2f((u16)(v.z & 0xffff)); f[5] = us2f((u16)(v.z >> 16));
    f[6] = us2f((u16)(v.w & 0xffff)); f[7] = us2f((u16)(v.w >> 16));
}

// ---------------------------------------------------------------------------
// K1 (MFMA GEMM): km/qm/xm = conv1x1 (r12 PASS, unchanged)
// ---------------------------------------------------------------------------
__global__ __launch_bounds__(256) void k_proj(
    const float* __restrict__ x, const float* __restrict__ vessel,
    const float* __restrict__ wk, const float* __restrict__ bk,
    const float* __restrict__ wq, const float* __restrict__ bq,
    const float* __restrict__ wx, const float* __restrict__ bx,
    bf16* __restrict__ km, bf16* __restrict__ qm, bf16* __restrict__ xm)
{
    __shared__ u16 xs[64 * 264];
    __shared__ u16 wsh[48 * 264];
    const int tid = threadIdx.x;
    const int bid = blockIdx.x;
    const int nh = bid & 1;
    const int pt = bid >> 1;
    const int b  = pt >> 6;
    const int p0 = (pt & 63) * 64;

#pragma unroll
    for (int i = 0; i < 16; ++i) {
        const int idx4 = tid + i * 256;
        const int ch = idx4 >> 4;
        const int px4 = (idx4 & 15) * 4;
        const float4 v = *(const float4*)&x[(b * 256 + ch) * 4096 + p0 + px4];
        xs[(px4 + 0) * 264 + ch] = f2u(v.x);
        xs[(px4 + 1) * 264 + ch] = f2u(v.y);
        xs[(px4 + 2) * 264 + ch] = f2u(v.z);
        xs[(px4 + 3) * 264 + ch] = f2u(v.w);
    }
#pragma unroll
    for (int i = 0; i < 12; ++i) {
        const int idx4 = tid + i * 256;
        const int o = idx4 >> 6;
        const int ch4 = (idx4 & 63) * 4;
        const int go = nh * 48 + o;
        const float* wp = (go < 32) ? wk : ((go < 64) ? wq : wx);
        const float4 v = *(const float4*)&wp[(go & 31) * 256 + ch4];
        wsh[o * 264 + ch4 + 0] = f2u(v.x);
        wsh[o * 264 + ch4 + 1] = f2u(v.y);
        wsh[o * 264 + ch4 + 2] = f2u(v.z);
        wsh[o * 264 + ch4 + 3] = f2u(v.w);
    }
    __syncthreads();

    const int w = tid >> 6;
    const int lane = tid & 63;
    const int lm = lane & 15, quad = lane >> 4;

    f32x4 acc0 = {0.f, 0.f, 0.f, 0.f};
    f32x4 acc1 = {0.f, 0.f, 0.f, 0.f};
    f32x4 acc2 = {0.f, 0.f, 0.f, 0.f};
#pragma unroll
    for (int kk = 0; kk < 8; ++kk) {
        const int k0 = kk * 32 + quad * 8;
        const bf16x8 a  = *(const bf16x8*)&xs[(w * 16 + lm) * 264 + k0];
        const bf16x8 b0 = *(const bf16x8*)&wsh[(0 + lm) * 264 + k0];
        const bf16x8 b1 = *(const bf16x8*)&wsh[(16 + lm) * 264 + k0];
        const bf16x8 b2 = *(const bf16x8*)&wsh[(32 + lm) * 264 + k0];
        acc0 = __builtin_amdgcn_mfma_f32_16x16x32_bf16(a, b0, acc0, 0, 0, 0);
        acc1 = __builtin_amdgcn_mfma_f32_16x16x32_bf16(a, b1, acc1, 0, 0, 0);
        acc2 = __builtin_amdgcn_mfma_f32_16x16x32_bf16(a, b2, acc2, 0, 0, 0);
    }
#pragma unroll
    for (int t = 0; t < 3; ++t) {
        const f32x4 acc = (t == 0) ? acc0 : ((t == 1) ? acc1 : acc2);
        const int go = nh * 48 + t * 16 + lm;
        const float* bs = (go < 32) ? bk : ((go < 64) ? bq : bx);
        const float bias = bs[go & 31];
        bf16* dst = (go < 32) ? km : ((go < 64) ? qm : xm);
#pragma unroll
        for (int rg = 0; rg < 4; ++rg) {
            const int px = p0 + w * 16 + quad * 4 + rg;
            float vv = acc[rg] + bias;
            if (go < 32) vv *= vessel[b * 4096 + px];
            dst[(b * 4096 + px) * 32 + (go & 31)] = __float2bfloat16(vv);
        }
    }
}

// ---------------------------------------------------------------------------
// K2 (MFMA): 4-scale local attention. Block = 4x8 px tile (32 px), grid 512.
// Phase A: S(32x192) = Q.K^T via mfma_16x16x32_bf16 (24 tiles, K=32).
// Phase B: e = exp(S) masked to window r<=4; ring sums -> Z3..Z9 (butterfly
// over 8 lanes/px); P[px][pos] = bf16(e * (iZ9 + r<=1?iZ3 + r<=2?iZ5 +
// r<=3?iZ7)) into kT's dead arena. Phase C: pre = P.X^T via MFMA (K=192).
// OOB halo: k=0 -> s=0 -> e=1 in denominators (matches reference zero-pad);
// x=0 contributes nothing. Scores stay f32; P bf16 (linear path only).
// LDS 54.5 KB -> 2 blocks/CU.
// ---------------------------------------------------------------------------
__global__ __launch_bounds__(256) void k_attn(
    const bf16* __restrict__ km, const bf16* __restrict__ qm,
    const bf16* __restrict__ xm, bf16* __restrict__ pre)
{
    __shared__ u16 kT[192 * 40];     // 15360 B; reused as P[32*200] after S
    __shared__ u16 qs[32 * 40];      //  2560 B
    __shared__ u16 xTt[32 * 200];    // 12800 B  [ch][pos]
    __shared__ float S[32 * 196];    // 25088 B  [px][pos]
    u16* P = kT;                     // P[px*200+pos], 12800 B, alias (kT dead)

    const int tid = threadIdx.x;
    const int b = blockIdx.x >> 7;
    const int t128 = blockIdx.x & 127;
    const int h0 = (t128 >> 3) * 4;          // 16 row-tiles of 4
    const int w0 = (t128 & 7) * 8;           // 8 col-tiles of 8
    const u16* uk = (const u16*)km;
    const u16* ux = (const u16*)xm;
    const uint4 z4 = {0u, 0u, 0u, 0u};

    // stage kT [pos][ch] + xTt [ch][pos] (transposed): 192 pos x 4 c8
#pragma unroll
    for (int i = 0; i < 3; ++i) {
        const int idx4 = tid + i * 256;      // 0..767
        const int pos = idx4 >> 2, c8 = idx4 & 3;
        const int gh = h0 - 4 + (pos >> 4), gw = w0 - 4 + (pos & 15);
        uint4 kv = z4, xv = z4;
        if (gh >= 0 && gh < 64 && gw >= 0 && gw < 64) {
            const int g = ((b << 12) + (gh << 6) + gw) * 32 + c8 * 8;
            kv = *(const uint4*)&uk[g];
            xv = *(const uint4*)&ux[g];
        }
        *(uint4*)&kT[pos * 40 + c8 * 8] = kv;
        const u16* xu = (const u16*)&xv;
#pragma unroll
        for (int t = 0; t < 8; ++t)
            xTt[(c8 * 8 + t) * 200 + pos] = xu[t];
    }
    if (tid < 128) {                         // 32 px x 4 c8 of Q
        const int px = tid >> 2, c8 = tid & 3;
        const int gh = h0 + (px >> 3), gw = w0 + (px & 7);
        const int g = ((b << 12) + (gh << 6) + gw) * 32 + c8 * 8;
        *(uint4*)&qs[px * 40 + c8 * 8] = *(const uint4*)&((const u16*)qm)[g];
    }
    __syncthreads();

    const int w = tid >> 6;
    const int lane = tid & 63;
    const int lm = lane & 15, quad = lane >> 4;

    // Phase A: S tiles. 24 tiles (m 0..1, n 0..11), wave w takes t=w+4i.
#pragma unroll
    for (int i = 0; i < 6; ++i) {
        const int t = w + i * 4;
        const int m = t / 12, n = t - m * 12;
        const bf16x8 a = *(const bf16x8*)&qs[(m * 16 + lm) * 40 + quad * 8];
        const bf16x8 bb = *(const bf16x8*)&kT[(n * 16 + lm) * 40 + quad * 8];
        f32x4 acc = {0.f, 0.f, 0.f, 0.f};
        acc = __builtin_amdgcn_mfma_f32_16x16x32_bf16(a, bb, acc, 0, 0, 0);
#pragma unroll
        for (int rg = 0; rg < 4; ++rg)
            S[(m * 16 + quad * 4 + rg) * 196 + n * 16 + lm] = acc[rg];
    }
    __syncthreads();

    // Phase B: per-thread 24 positions of one pixel
    const int px = tid >> 3, cg = tid & 7;
    const int ty = px >> 3, tx = px & 7;
    float e[24];
    float Z3 = 0.f, Z5 = 0.f, Z7 = 0.f, Z9 = 0.f;
#pragma unroll
    for (int i = 0; i < 24; ++i) {
        const int pos = cg + 8 * i;
        const int hy = pos >> 4, hx = pos & 15;
        const int dy = hy - 4 - ty, dx = hx - 4 - tx;
        const int ady = dy < 0 ? -dy : dy, adx = dx < 0 ? -dx : dx;
        const int r = ady > adx ? ady : adx;
        const float s = S[px * 196 + pos];
        const float ev = (r <= 4) ? __expf(s) : 0.f;
        e[i] = ev;
        if (r <= 1) Z3 += ev;
        if (r <= 2) Z5 += ev;
        if (r <= 3) Z7 += ev;
        Z9 += ev;
    }
#pragma unroll
    for (int m = 1; m <= 4; m <<= 1) {
        Z3 += __shfl_xor(Z3, m);
        Z5 += __shfl_xor(Z5, m);
        Z7 += __shfl_xor(Z7, m);
        Z9 += __shfl_xor(Z9, m);
    }
    const float iZ3 = 1.f / Z3, iZ5 = 1.f / Z5, iZ7 = 1.f / Z7, iZ9 = 1.f / Z9;
#pragma unroll
    for (int i = 0; i < 24; ++i) {
        const int pos = cg + 8 * i;
        const int hy = pos >> 4, hx = pos & 15;
        const int dy = hy - 4 - ty, dx = hx - 4 - tx;
        const int ady = dy < 0 ? -dy : dy, adx = dx < 0 ? -dx : dx;
        const int r = ady > adx ? ady : adx;
        float coef = iZ9;
        if (r <= 1) coef += iZ3;
        if (r <= 2) coef += iZ5;
        if (r <= 3) coef += iZ7;
        P[px * 200 + pos] = f2u(e[i] * coef);
    }
    __syncthreads();

    // Phase C: pre(32x32) = P(32x192) . X^T : wave w -> tile (m0,n0)
    const int m0 = w >> 1, n0 = w & 1;
    f32x4 acc = {0.f, 0.f, 0.f, 0.f};
#pragma unroll
    for (int kk = 0; kk < 6; ++kk) {
        const int k0 = kk * 32 + quad * 8;
        const bf16x8 a = *(const bf16x8*)&P[(m0 * 16 + lm) * 200 + k0];
        const bf16x8 bb = *(const bf16x8*)&xTt[(n0 * 16 + lm) * 200 + k0];
        acc = __builtin_amdgcn_mfma_f32_16x16x32_bf16(a, bb, acc, 0, 0, 0);
    }
#pragma unroll
    for (int rg = 0; rg < 4; ++rg) {
        const int pl = m0 * 16 + quad * 4 + rg;
        const int gh = h0 + (pl >> 3), gw = w0 + (pl & 7);
        pre[(((b << 12) + (gh << 6) + gw) << 5) + n0 * 16 + lm] =
            __float2bfloat16(acc[rg]);
    }
}

// ---------------------------------------------------------------------------
// K2b: partial S2 = pre^T pre (32x32) + S1 = sum(pre), 256 px/blk (unchanged)
// ---------------------------------------------------------------------------
__global__ __launch_bounds__(256) void k_cov(
    const bf16* __restrict__ pre, float* __restrict__ partials)
{
    __shared__ float t[256 * 32];
    const int tid = threadIdx.x;
    const int p0 = blockIdx.x * 256;
    for (int i = 0; i < 32; ++i) {
        const int idx = tid + i * 256;
        t[idx] = bf2f(pre[p0 * 32 + idx]);
    }
    __syncthreads();
    const int i0 = tid >> 3, j0 = (tid & 7) * 4;
    float4 a = {0.f, 0.f, 0.f, 0.f};
    for (int p = 0; p < 256; ++p) {
        const float vi = t[p * 32 + i0];
        const float4 vj = *(const float4*)&t[p * 32 + j0];
        a.x += vi * vj.x; a.y += vi * vj.y; a.z += vi * vj.z; a.w += vi * vj.w;
    }
    *(float4*)&partials[blockIdx.x * 1056 + i0 * 32 + j0] = a;
    if (tid < 32) {
        float s = 0.f;
        for (int p = 0; p < 256; ++p) s += t[p * 32 + tid];
        partials[blockIdx.x * 1056 + 1024 + tid] = s;
    }
}

// ---------------------------------------------------------------------------
// K2c: BN constants (unchanged)
// ---------------------------------------------------------------------------
__global__ __launch_bounds__(256) void k_stats(
    const float* __restrict__ partials, const float* __restrict__ wf,
    const float* __restrict__ bfb, const float* __restrict__ gamma,
    const float* __restrict__ beta,
    float* __restrict__ Aout, float* __restrict__ Sout)
{
    __shared__ float cov[1024];
    __shared__ float mu[32];
    const int tid = threadIdx.x;
    float4 a = {0.f, 0.f, 0.f, 0.f};
    for (int blk = 0; blk < 64; ++blk) {
        const float4 p = *(const float4*)&partials[blk * 1056 + tid * 4];
        a.x += p.x; a.y += p.y; a.z += p.z; a.w += p.w;
    }
    *(float4*)&cov[tid * 4] = a;
    if (tid < 32) {
        float s = 0.f;
        for (int blk = 0; blk < 64; ++blk) s += partials[blk * 1056 + 1024 + tid];
        mu[tid] = s * (1.f / 16384.f);
    }
    __syncthreads();
    float wo[32];
#pragma unroll
    for (int c = 0; c < 32; ++c) wo[c] = wf[tid * 32 + c];
    float mv = 0.f;
#pragma unroll
    for (int c = 0; c < 32; ++c) mv += wo[c] * mu[c];
    float qacc = 0.f;
    for (int i2 = 0; i2 < 32; ++i2) {
        float t = 0.f;
#pragma unroll
        for (int j2 = 0; j2 < 32; ++j2) t += wo[j2] * cov[i2 * 32 + j2];
        qacc += wo[i2] * t;
    }
    const float var = qacc * (1.f / 16384.f) - mv * mv;
    const float A = gamma[tid] * rsqrtf(var + 1e-5f);
    Aout[tid] = A;
    Sout[tid] = beta[tid] - A * (mv + bfb[tid]);
}

// ---------------------------------------------------------------------------
// K3: out = x + A*(wf.pre + bf) + S, f32 out (unchanged)
// ---------------------------------------------------------------------------
__global__ __launch_bounds__(256) void k_out(
    const bf16* __restrict__ pre, const float* __restrict__ wf,
    const float* __restrict__ bfb, const float* __restrict__ x,
    const float* __restrict__ A, const float* __restrict__ S,
    float* __restrict__ out)
{
    __shared__ float wfL[256 * 32];
    __shared__ float pL[64 * 36];
    const int tid = threadIdx.x;
    const int gp0 = blockIdx.x * 64;
    const int b = gp0 >> 12, p0 = gp0 & 4095;
#pragma unroll
    for (int i = 0; i < 8; ++i) {
        const int idx4 = tid + i * 256;
        *(float4*)&wfL[idx4 * 4] = *(const float4*)&wf[idx4 * 4];
    }
    for (int i = 0; i < 8; ++i) {
        const int idx = tid + i * 256;
        const int p = idx >> 5, c = idx & 31;
        pL[p * 36 + c] = bf2f(pre[gp0 * 32 + idx]);
    }
    __syncthreads();
    const int og = tid >> 6, px = tid & 63;
    float4 pv[8];
#pragma unroll
    for (int c4 = 0; c4 < 8; ++c4)
        pv[c4] = *(const float4*)&pL[px * 36 + c4 * 4];
#pragma unroll
    for (int g = 0; g < 4; ++g) {
        float acc[16];
#pragma unroll
        for (int jj = 0; jj < 16; ++jj) acc[jj] = bfb[og * 64 + g * 16 + jj];
#pragma unroll
        for (int c4 = 0; c4 < 8; ++c4) {
            const float4 xv = pv[c4];
#pragma unroll
            for (int jj = 0; jj < 16; ++jj) {
                const float4 wv = *(const float4*)&wfL[(og * 64 + g * 16 + jj) * 32 + c4 * 4];
                acc[jj] += wv.x * xv.x + wv.y * xv.y + wv.z * xv.z + wv.w * xv.w;
            }
        }
#pragma unroll
        for (int jj = 0; jj < 16; ++jj) {
            const int o = og * 64 + g * 16 + jj;
            const int ga = ((b << 8) + o) * 4096 + p0 + px;
            out[ga] = x[ga] + A[o] * acc[jj] + S[o];
        }
    }
}

extern "C" void kernel_launch(void* const* d_in, const int* in_sizes, int n_in,
                              void* d_out, int out_size, void* d_ws, size_t ws_size,
                              hipStream_t stream)
{
    (void)in_sizes; (void)n_in; (void)out_size; (void)ws_size;
    float* out = (float*)d_out;
    char* ws = (char*)d_ws;

    const float* x      = (const float*)d_in[0];
    const float* vessel = (const float*)d_in[1];
    const float* wk     = (const float*)d_in[2];
    const float* bk     = (const float*)d_in[3];
    const float* wq     = (const float*)d_in[4];
    const float* bq     = (const float*)d_in[5];
    const float* wx     = (const float*)d_in[6];
    const float* bx     = (const float*)d_in[7];
    const float* wf     = (const float*)d_in[8];
    const float* bfb    = (const float*)d_in[9];
    const float* gamma  = (const float*)d_in[10];
    const float* beta   = (const float*)d_in[11];

    bf16* km  = (bf16*)(ws);
    bf16* qm  = (bf16*)(ws + 1048576);
    bf16* xm  = (bf16*)(ws + 2097152);
    bf16* pre = (bf16*)(ws + 3145728);
    float* partials = (float*)(ws + 4194304);
    float* Abuf     = (float*)(ws + 4464640);
    float* Sbuf     = (float*)(ws + 4465664);

    k_proj <<<512, 256, 0, stream>>>(x, vessel, wk, bk, wq, bq, wx, bx,
                                     km, qm, xm);
    k_attn <<<512, 256, 0, stream>>>(km, qm, xm, pre);
    k_cov  <<< 64, 256, 0, stream>>>(pre, partials);
    k_stats<<<  1, 256, 0, stream>>>(partials, wf, bfb, gamma, beta, Abuf, Sbuf);
    k_out  <<<256, 256, 0, stream>>>(pre, wf, bfb, x, Abuf, Sbuf, out);
}